// Round 2
// baseline (243.231 us; speedup 1.0000x reference)
//
#include <hip/hip_runtime.h>

// Problem constants (fixed by setup_inputs): B=8, S=4096, H=1024
constexpr int Bn  = 8;
constexpr int Sn  = 4096;
constexpr int Nn  = Bn * Sn;          // 32768 labels
constexpr int Hn  = 1024;
constexpr int TPB = 1024;             // block size (copy blocks and scan block)
constexpr int PER = Nn / TPB;         // 32 labels per thread in the scan block
constexpr int NW  = TPB / 64;         // 16 waves per block

constexpr size_t FEAT_ELEMS = (size_t)Nn * Hn;        // 33,554,432 floats
constexpr size_t FEAT_VEC4  = FEAT_ELEMS / 4;         // 8,388,608 float4
constexpr int    VEC_PER_T  = 8;                      // float4 per copy thread
constexpr int    COPY_BLOCKS = (int)(FEAT_VEC4 / ((size_t)TPB * VEC_PER_T)); // 1024

// Fused kernel:
//   blocks [0, COPY_BLOCKS): float4 strided copy of sequence_output -> out
//   block COPY_BLOCKS:       single-block prefix-sum scan producing segment ids
// The scan block is independent of the copy, so it runs concurrently on a
// spare CU instead of serializing after the 134 MB copy.
__global__ __launch_bounds__(TPB) void fused_kernel(const float* __restrict__ seq,
                                                    const int* __restrict__ labels,
                                                    float* __restrict__ out) {
    if (blockIdx.x < COPY_BLOCKS) {
        // ---- copy part: 16 B/lane, grid-strided, fully coalesced ----
        const float4* __restrict__ src = reinterpret_cast<const float4*>(seq);
        float4* __restrict__ dst       = reinterpret_cast<float4*>(out);
        const size_t base   = (size_t)blockIdx.x * TPB + threadIdx.x;
        const size_t stride = (size_t)COPY_BLOCKS * TPB;
#pragma unroll
        for (int i = 0; i < VEC_PER_T; ++i) {
            const size_t idx = base + (size_t)i * stride;
            dst[idx] = src[idx];
        }
        return;
    }

    // ---- scan part: one block computes all 32768 segment ids ----
    __shared__ int wave_sums[NW];
    __shared__ int extra_off_sh[Bn];

    float* __restrict__ seg_out = out + FEAT_ELEMS;

    const int tid  = threadIdx.x;
    const int lane = tid & 63;
    const int wave = tid >> 6;
    const int base = tid * PER;

    // Load this thread's 32 contiguous labels (int4-vectorized, 16B aligned)
    int inc[PER];
    int sum = 0;
    const int4* l4 = reinterpret_cast<const int4*>(labels + base);
#pragma unroll
    for (int i = 0; i < PER / 4; ++i) {
        int4 v = l4[i];
        inc[4 * i + 0] = (v.x == 0); sum += inc[4 * i + 0];
        inc[4 * i + 1] = (v.y == 0); sum += inc[4 * i + 1];
        inc[4 * i + 2] = (v.z == 0); sum += inc[4 * i + 2];
        inc[4 * i + 3] = (v.w == 0); sum += inc[4 * i + 3];
    }

    // Wave64 inclusive scan of per-thread sums
    int incl = sum;
#pragma unroll
    for (int off = 1; off < 64; off <<= 1) {
        int u = __shfl_up(incl, off, 64);
        if (lane >= off) incl += u;
    }
    if (lane == 63) wave_sums[wave] = incl;

    // Tiny serial job: exclusive scan of the 8 per-example "extra" bits
    if (tid == 0) {
        int acc = 0;
#pragma unroll
        for (int b = 0; b < Bn; ++b) {
            extra_off_sh[b] = acc;
            acc += (labels[b * Sn + Sn - 1] == 1);
        }
    }
    __syncthreads();

    // One wave scans the 16 wave totals
    if (wave == 0) {
        int v = (lane < NW) ? wave_sums[lane] : 0;
#pragma unroll
        for (int off = 1; off < NW; off <<= 1) {
            int u = __shfl_up(v, off, 64);
            if (lane >= off) v += u;
        }
        if (lane < NW) wave_sums[lane] = v;
    }
    __syncthreads();

    // Exclusive prefix for this thread's first element, then serial write-out.
    // Segment ids (max ~16.4k) are exact in fp32.
    int excl = (wave ? wave_sums[wave - 1] : 0) + (incl - sum);
#pragma unroll
    for (int i = 0; i < PER; ++i) {
        int idx = base + i;
        seg_out[idx] = (float)(excl + extra_off_sh[idx >> 12]);  // idx>>12 == idx / Sn
        excl += inc[i];
    }
}

extern "C" void kernel_launch(void* const* d_in, const int* in_sizes, int n_in,
                              void* d_out, int out_size, void* d_ws, size_t ws_size,
                              hipStream_t stream) {
    const float* seq    = (const float*)d_in[0];  // [B,S,H] fp32
    const int*   labels = (const int*)d_in[1];    // [B,S] int
    float*       out    = (float*)d_out;

    fused_kernel<<<COPY_BLOCKS + 1, TPB, 0, stream>>>(seq, labels, out);
}

// Round 3
// 229.628 us; speedup vs baseline: 1.0592x; 1.0592x over previous
//
#include <hip/hip_runtime.h>

// Problem constants (fixed by setup_inputs): B=8, S=4096, H=1024
constexpr int Bn  = 8;
constexpr int Sn  = 4096;
constexpr int Nn  = Bn * Sn;          // 32768 labels
constexpr int Hn  = 1024;

constexpr int TPB = 256;              // block size (copy blocks and scan block)
constexpr int NW  = TPB / 64;         // 4 waves in scan block
constexpr int PER = Nn / TPB;         // 128 labels per scan thread

constexpr size_t FEAT_ELEMS = (size_t)Nn * Hn;        // 33,554,432 floats
constexpr size_t FEAT_VEC4  = FEAT_ELEMS / 4;         // 8,388,608 float4
constexpr int    VEC_PER_T  = 4;                      // float4 per copy thread
constexpr int    COPY_BLOCKS = (int)(FEAT_VEC4 / ((size_t)TPB * VEC_PER_T)); // 8192

// Fused kernel:
//   block 0:                single-block prefix-sum scan producing segment ids
//                           (dispatched first -> overlaps the copy, no tail)
//   blocks [1, COPY_BLOCKS]: each copies one CONTIGUOUS 16 KB chunk
//                           (4 hoisted float4 per thread, lane-coalesced)
__global__ __launch_bounds__(TPB) void fused_kernel(const float* __restrict__ seq,
                                                    const int* __restrict__ labels,
                                                    float* __restrict__ out) {
    if (blockIdx.x > 0) {
        // ---- copy part: block-contiguous chunk, loads hoisted before stores ----
        const float4* __restrict__ src = reinterpret_cast<const float4*>(seq);
        float4* __restrict__ dst       = reinterpret_cast<float4*>(out);
        const size_t base = (size_t)(blockIdx.x - 1) * (TPB * VEC_PER_T) + threadIdx.x;
        float4 r0 = src[base + 0 * TPB];
        float4 r1 = src[base + 1 * TPB];
        float4 r2 = src[base + 2 * TPB];
        float4 r3 = src[base + 3 * TPB];
        dst[base + 0 * TPB] = r0;
        dst[base + 1 * TPB] = r1;
        dst[base + 2 * TPB] = r2;
        dst[base + 3 * TPB] = r3;
        return;
    }

    // ---- scan part (block 0): all 32768 segment ids, 128 labels/thread ----
    __shared__ int wave_sums[NW];
    __shared__ int extra_off_sh[Bn];

    float* __restrict__ seg_out = out + FEAT_ELEMS;

    const int tid  = threadIdx.x;
    const int lane = tid & 63;
    const int wave = tid >> 6;
    const int base = tid * PER;

    // Pass 1: count zeros in this thread's 128 contiguous labels (int4 loads)
    const int4* l4 = reinterpret_cast<const int4*>(labels + base);
    int sum = 0;
#pragma unroll
    for (int i = 0; i < PER / 4; ++i) {
        int4 v = l4[i];
        sum += (v.x == 0) + (v.y == 0) + (v.z == 0) + (v.w == 0);
    }

    // Wave64 inclusive scan of per-thread sums
    int incl = sum;
#pragma unroll
    for (int off = 1; off < 64; off <<= 1) {
        int u = __shfl_up(incl, off, 64);
        if (lane >= off) incl += u;
    }
    if (lane == 63) wave_sums[wave] = incl;

    // Tiny serial job: exclusive scan of the 8 per-example "extra" bits
    if (tid == 0) {
        int acc = 0;
#pragma unroll
        for (int b = 0; b < Bn; ++b) {
            extra_off_sh[b] = acc;
            acc += (labels[b * Sn + Sn - 1] == 1);
        }
    }
    __syncthreads();

    // One wave scans the 4 wave totals
    if (wave == 0) {
        int v = (lane < NW) ? wave_sums[lane] : 0;
#pragma unroll
        for (int off = 1; off < NW; off <<= 1) {
            int u = __shfl_up(v, off, 64);
            if (lane >= off) v += u;
        }
        if (lane < NW) wave_sums[lane] = v;
    }
    __syncthreads();

    // Pass 2: reload labels (L2-hot), emit exclusive prefix as fp32.
    // Segment ids (max ~16.4k) are exact in fp32.
    int excl = (wave ? wave_sums[wave - 1] : 0) + (incl - sum);
#pragma unroll
    for (int i = 0; i < PER / 4; ++i) {
        int4 v = l4[i];
        int idx = base + 4 * i;
        int eo  = extra_off_sh[idx >> 12];     // idx>>12 == idx / Sn (Sn=4096)
        seg_out[idx + 0] = (float)(excl + eo); excl += (v.x == 0);
        eo = extra_off_sh[(idx + 1) >> 12];
        seg_out[idx + 1] = (float)(excl + eo); excl += (v.y == 0);
        eo = extra_off_sh[(idx + 2) >> 12];
        seg_out[idx + 2] = (float)(excl + eo); excl += (v.z == 0);
        eo = extra_off_sh[(idx + 3) >> 12];
        seg_out[idx + 3] = (float)(excl + eo); excl += (v.w == 0);
    }
}

extern "C" void kernel_launch(void* const* d_in, const int* in_sizes, int n_in,
                              void* d_out, int out_size, void* d_ws, size_t ws_size,
                              hipStream_t stream) {
    const float* seq    = (const float*)d_in[0];  // [B,S,H] fp32
    const int*   labels = (const int*)d_in[1];    // [B,S] int
    float*       out    = (float*)d_out;

    fused_kernel<<<COPY_BLOCKS + 1, TPB, 0, stream>>>(seq, labels, out);
}

// Round 5
// 220.487 us; speedup vs baseline: 1.1032x; 1.0415x over previous
//
#include <hip/hip_runtime.h>

// Problem constants (fixed by setup_inputs): B=8, S=4096, H=1024
constexpr int Bn  = 8;
constexpr int Sn  = 4096;
constexpr int Nn  = Bn * Sn;          // 32768 labels
constexpr int Hn  = 1024;

constexpr int TPB = 256;              // block size (copy blocks and scan block)
constexpr int NW  = TPB / 64;         // 4 waves in scan block
constexpr int PER = Nn / TPB;         // 128 labels per scan thread

constexpr size_t FEAT_ELEMS = (size_t)Nn * Hn;        // 33,554,432 floats
constexpr size_t FEAT_VEC4  = FEAT_ELEMS / 4;         // 8,388,608 float4
constexpr int    VEC_PER_T  = 8;                      // float4 per copy thread
constexpr int    COPY_BLOCKS = (int)(FEAT_VEC4 / ((size_t)TPB * VEC_PER_T)); // 4096

// Native clang vector type — required by __builtin_nontemporal_load/store
// (HIP's float4 is a struct wrapper and is rejected).
typedef float v4f __attribute__((ext_vector_type(4)));

// Fused kernel:
//   block 0:                 single-block prefix-sum scan producing segment ids
//                            (dispatched first -> overlaps the copy, no tail)
//   blocks [1, COPY_BLOCKS]: each copies one CONTIGUOUS 32 KB chunk.
//                            All 8 float4 loads hoisted (8 outstanding/thread),
//                            nontemporal on both streams (zero reuse -> skip
//                            L2 allocation).
__global__ __launch_bounds__(TPB) void fused_kernel(const float* __restrict__ seq,
                                                    const int* __restrict__ labels,
                                                    float* __restrict__ out) {
    if (blockIdx.x > 0) {
        const v4f* __restrict__ src = reinterpret_cast<const v4f*>(seq);
        v4f* __restrict__ dst       = reinterpret_cast<v4f*>(out);
        const size_t base = (size_t)(blockIdx.x - 1) * (TPB * VEC_PER_T) + threadIdx.x;
        v4f r[VEC_PER_T];
#pragma unroll
        for (int i = 0; i < VEC_PER_T; ++i)
            r[i] = __builtin_nontemporal_load(&src[base + (size_t)i * TPB]);
#pragma unroll
        for (int i = 0; i < VEC_PER_T; ++i)
            __builtin_nontemporal_store(r[i], &dst[base + (size_t)i * TPB]);
        return;
    }

    // ---- scan part (block 0): all 32768 segment ids, 128 labels/thread ----
    __shared__ int wave_sums[NW];
    __shared__ int extra_off_sh[Bn];

    float* __restrict__ seg_out = out + FEAT_ELEMS;

    const int tid  = threadIdx.x;
    const int lane = tid & 63;
    const int wave = tid >> 6;
    const int base = tid * PER;

    // Pass 1: count zeros in this thread's 128 contiguous labels (int4 loads)
    const int4* l4 = reinterpret_cast<const int4*>(labels + base);
    int sum = 0;
#pragma unroll
    for (int i = 0; i < PER / 4; ++i) {
        int4 v = l4[i];
        sum += (v.x == 0) + (v.y == 0) + (v.z == 0) + (v.w == 0);
    }

    // Wave64 inclusive scan of per-thread sums
    int incl = sum;
#pragma unroll
    for (int off = 1; off < 64; off <<= 1) {
        int u = __shfl_up(incl, off, 64);
        if (lane >= off) incl += u;
    }
    if (lane == 63) wave_sums[wave] = incl;

    // Tiny serial job: exclusive scan of the 8 per-example "extra" bits
    if (tid == 0) {
        int acc = 0;
#pragma unroll
        for (int b = 0; b < Bn; ++b) {
            extra_off_sh[b] = acc;
            acc += (labels[b * Sn + Sn - 1] == 1);
        }
    }
    __syncthreads();

    // One wave scans the 4 wave totals
    if (wave == 0) {
        int v = (lane < NW) ? wave_sums[lane] : 0;
#pragma unroll
        for (int off = 1; off < NW; off <<= 1) {
            int u = __shfl_up(v, off, 64);
            if (lane >= off) v += u;
        }
        if (lane < NW) wave_sums[lane] = v;
    }
    __syncthreads();

    // Pass 2: reload labels (L2-hot), emit exclusive prefix as fp32.
    // Segment ids (max ~16.4k) are exact in fp32.
    int excl = (wave ? wave_sums[wave - 1] : 0) + (incl - sum);
#pragma unroll
    for (int i = 0; i < PER / 4; ++i) {
        int4 v = l4[i];
        int idx = base + 4 * i;
        int eo  = extra_off_sh[idx >> 12];     // idx>>12 == idx / Sn (Sn=4096)
        seg_out[idx + 0] = (float)(excl + eo); excl += (v.x == 0);
        eo = extra_off_sh[(idx + 1) >> 12];
        seg_out[idx + 1] = (float)(excl + eo); excl += (v.y == 0);
        eo = extra_off_sh[(idx + 2) >> 12];
        seg_out[idx + 2] = (float)(excl + eo); excl += (v.z == 0);
        eo = extra_off_sh[(idx + 3) >> 12];
        seg_out[idx + 3] = (float)(excl + eo); excl += (v.w == 0);
    }
}

extern "C" void kernel_launch(void* const* d_in, const int* in_sizes, int n_in,
                              void* d_out, int out_size, void* d_ws, size_t ws_size,
                              hipStream_t stream) {
    const float* seq    = (const float*)d_in[0];  // [B,S,H] fp32
    const int*   labels = (const int*)d_in[1];    // [B,S] int
    float*       out    = (float*)d_out;

    fused_kernel<<<COPY_BLOCKS + 1, TPB, 0, stream>>>(seq, labels, out);
}